// Round 10
// baseline (61.145 us; speedup 1.0000x reference)
//
#include <hip/hip_runtime.h>
#include <hip/hip_bf16.h>
#include <stdint.h>

#define NTOK 4096
#define DIM  256
#define HID  1024
#define NEXP 8
#define MTILE 32
#define HC 32
#define HSLICE 512
#define NSLICE 2
#define NCHUNK (HSLICE / HC)   // 16

typedef float f32x4 __attribute__((ext_vector_type(4)));
typedef short s16x8 __attribute__((ext_vector_type(8)));

__device__ __forceinline__ unsigned short f2bf(float f) {
  union { float f; unsigned u; } v; v.f = f;
  unsigned r = v.u + 0x7FFFu + ((v.u >> 16) & 1u);
  return (unsigned short)(r >> 16);
}
__device__ __forceinline__ float bf2f(unsigned short s) {
  union { float f; unsigned u; } v; v.u = ((unsigned)s) << 16;
  return v.f;
}
__device__ __forceinline__ void mfma16(f32x4& acc, s16x8 a, s16x8 b) {
  asm("v_mfma_f32_16x16x32_bf16 %0, %1, %2, %0" : "+v"(acc) : "v"(a), "v"(b));
}
__device__ __forceinline__ void accfence(f32x4& a) {   // MFMA->VALU read hazard
  asm volatile("s_nop 7" : "+v"(a));
}
__device__ __forceinline__ void initfence(f32x4& a) {  // VALU init -> MFMA srcC hazard
  asm volatile("s_nop 1" : "+v"(a));
}

// ---- merged prep: transpose + bf16 + swizzle; zero counts ----
// W1 [E][256][1024] f32 -> W1T [E][1024][256] bf16, col' = col ^ ((row&7)<<3)
// W2 [E][1024][256] f32 -> W2T chunk-tiled [E][H/32][D][32] bf16, CONTIGUOUS 16 KB
//   per (e,chunk); within a d-row the 8-elem slot is XORed: slot' = slot ^ ((d>>1)&3)
__global__ __launch_bounds__(256) void prep(const float* __restrict__ W1,
                                            const float* __restrict__ W2,
                                            unsigned short* __restrict__ W1T,
                                            unsigned short* __restrict__ W2T,
                                            int* __restrict__ counts) {
  __shared__ float tile[32][33];
  int id = blockIdx.x;
  int tx = threadIdx.x, ty = threadIdx.y;
  if (id == 0 && ty == 0 && tx < NEXP) counts[tx] = 0;

  const float* in; unsigned short* out; int R, C, bx, by, e, sw;
  if (id < 2048) {            // W1 job: in R=256 x C=1024
    e = id >> 8; int rem = id & 255; by = rem >> 5; bx = rem & 31;
    in = W1; out = W1T; R = 256; C = 1024; sw = 1;
  } else {                    // W2 job: in R=1024 x C=256
    int id2 = id - 2048;
    e = id2 >> 8; int rem = id2 & 255; by = (rem >> 3) & 31; bx = rem & 7;
    in = W2; out = W2T; R = 1024; C = 256; sw = 0;
  }
  int r0 = by * 32, c0 = bx * 32;
  const float* ip = in + (size_t)e * R * C;
  unsigned short* op = out + (size_t)e * R * C;
  #pragma unroll
  for (int k = 0; k < 4; ++k)
    tile[ty + 8*k][tx] = ip[(size_t)(r0 + ty + 8*k) * C + c0 + tx];
  __syncthreads();
  #pragma unroll
  for (int k = 0; k < 4; ++k) {
    float v = tile[tx][ty + 8*k];
    if (sw) {
      int row = c0 + ty + 8*k;   // h
      int col = r0 + tx;         // d
      op[(size_t)row * R + (col ^ ((row & 7) << 3))] = f2bf(v);
    } else {
      int d = c0 + ty + 8*k;     // output d (input col)
      int h = r0 + tx;           // input row
      int ch = h >> 5, kk = h & 31;
      int slot = (kk >> 3) ^ ((d >> 1) & 3);
      op[(size_t)ch * (DIM * 32) + d * 32 + slot * 8 + (kk & 7)] = f2bf(v);
    }
  }
}

// ---- gate + top-2 + block-aggregated routing (16 tokens/block, 16 lanes/token) ----
// list entries encode token*2 + slot
__global__ __launch_bounds__(256) void gate_route(const float* __restrict__ x,
    const float* __restrict__ gW, const float* __restrict__ gb,
    const float* __restrict__ temp,
    int* __restrict__ counts, int* __restrict__ list,
    unsigned short* __restrict__ xbf) {
  __shared__ int pairs[16][2];
  __shared__ int lcnt[NEXP], lbase[NEXP], lrank[NEXP];
  int tid = threadIdx.x;
  int w = tid >> 6, lane = tid & 63;
  int sl = lane & 15, g = lane >> 4;
  if (tid < NEXP) { lcnt[tid] = 0; lrank[tid] = 0; }
  __syncthreads();
  int t0 = blockIdx.x * 16;
  int tok = w * 4 + g;
  int n = t0 + tok;

  float4 xv[4];
  #pragma unroll
  for (int p = 0; p < 4; ++p)
    xv[p] = *reinterpret_cast<const float4*>(x + (size_t)n * DIM + sl * 16 + p * 4);
  {
    s16x8 xb0, xb1;
    xb0[0]=(short)f2bf(xv[0].x); xb0[1]=(short)f2bf(xv[0].y); xb0[2]=(short)f2bf(xv[0].z); xb0[3]=(short)f2bf(xv[0].w);
    xb0[4]=(short)f2bf(xv[1].x); xb0[5]=(short)f2bf(xv[1].y); xb0[6]=(short)f2bf(xv[1].z); xb0[7]=(short)f2bf(xv[1].w);
    xb1[0]=(short)f2bf(xv[2].x); xb1[1]=(short)f2bf(xv[2].y); xb1[2]=(short)f2bf(xv[2].z); xb1[3]=(short)f2bf(xv[2].w);
    xb1[4]=(short)f2bf(xv[3].x); xb1[5]=(short)f2bf(xv[3].y); xb1[6]=(short)f2bf(xv[3].z); xb1[7]=(short)f2bf(xv[3].w);
    *reinterpret_cast<s16x8*>(xbf + (size_t)n * DIM + sl * 16)     = xb0;
    *reinterpret_cast<s16x8*>(xbf + (size_t)n * DIM + sl * 16 + 8) = xb1;
  }
  float acc[NEXP];
  #pragma unroll
  for (int e = 0; e < NEXP; ++e) {
    const float* we = gW + (size_t)e * DIM + sl * 16;
    float a = 0.f;
    #pragma unroll
    for (int p = 0; p < 4; ++p) {
      float4 wv = *reinterpret_cast<const float4*>(we + p * 4);
      a += xv[p].x*wv.x + xv[p].y*wv.y + xv[p].z*wv.z + xv[p].w*wv.w;
    }
    acc[e] = a;
  }
  #pragma unroll
  for (int off = 1; off < 16; off <<= 1) {
    #pragma unroll
    for (int e = 0; e < NEXP; ++e) acc[e] += __shfl_xor(acc[e], off);
  }
  if (sl == 0) {
    float t = temp[0];
    float s[NEXP];
    #pragma unroll
    for (int e = 0; e < NEXP; ++e) s[e] = (acc[e] + gb[e]) / t;
    int b0 = 0; float v0 = s[0];
    #pragma unroll
    for (int e = 1; e < NEXP; ++e) if (s[e] > v0) { v0 = s[e]; b0 = e; }
    int b1i = 0; float v1 = -3.4e38f;
    #pragma unroll
    for (int e = 0; e < NEXP; ++e) if (e != b0 && s[e] > v1) { v1 = s[e]; b1i = e; }
    pairs[tok][0] = b0;
    pairs[tok][1] = b1i;
    atomicAdd(&lcnt[b0], 1);
    atomicAdd(&lcnt[b1i], 1);
  }
  __syncthreads();
  if (tid < NEXP) lbase[tid] = atomicAdd(&counts[tid], lcnt[tid]);
  __syncthreads();
  if (tid < 32) {
    int tk = tid >> 1;
    int e = pairs[tk][tid & 1];
    int r = atomicAdd(&lrank[e], 1);
    list[e * NTOK + lbase[e] + r] = (t0 + tk) * 2 + (tid & 1);
  }
}

// ---- fused FFN: 4 waves, X in regs, W1+W2 dbuf LDS, depth-2 pipeline,
//      both weight stages now wave-contiguous (m97 pattern) ----
__global__ __launch_bounds__(256, 2) void moe_ffn(
    const unsigned short* __restrict__ xbf,
    const unsigned short* __restrict__ W1T,  // [E][H][D] bf16, swizzled
    const unsigned short* __restrict__ W2T,  // [E][H/32][D][32] bf16, chunk-tiled
    const float* __restrict__ b1g, const float* __restrict__ b2g,
    const int* __restrict__ counts, const int* __restrict__ list,
    unsigned short* __restrict__ ybuf) {
  int b = blockIdx.x;
  int e = b & 7;
  int r = b >> 3;
  int s = r & (NSLICE - 1);
  int t = r >> 1;
  int cnt = counts[e];
  if (t * MTILE >= cnt) return;

  __shared__ __align__(16) short W1b[2][HC * 256];   // 32 KB
  __shared__ __align__(16) short W2b[2][256 * HC];   // 32 KB
  __shared__ __align__(16) short hs[2][32][40];      // 5 KB
  __shared__ float b1s[HSLICE];                      // 2 KB

  int tid = threadIdx.x;
  int l = tid & 63, w = tid >> 6;
  int lr = l & 15, lg = l >> 4, kg = lg * 8;
  int wm = w & 1, wn = w >> 1;   // GEMM1: tok-half16 x hcol-group16; GEMM2: tok-half16 x d-half128
  int hbase = s * HSLICE;
  const int* mylist = list + e * NTOK + t * MTILE;
  const unsigned short* W1e = W1T + (size_t)e * HID * DIM;
  const unsigned short* W2e = W2T + (size_t)e * HID * DIM;

  auto stage = [&](int hc, int buf) {   // 16 KB W1 + 16 KB W2, both linear memcpy
    const char* src1 = (const char*)(W1e + (size_t)hc * DIM);
    char* dst1 = (char*)&W1b[buf][0];
    const char* src2 = (const char*)(W2e + (size_t)(hc >> 5) * (DIM * 32));
    char* dst2 = (char*)&W2b[buf][0];
    #pragma unroll
    for (int i = 0; i < 4; ++i) {
      int off = w * 4096 + i * 1024;
      __builtin_amdgcn_global_load_lds(
        (const __attribute__((address_space(1))) void*)(src1 + off + l * 16),
        (__attribute__((address_space(3))) void*)(dst1 + off), 16, 0, 0);
      __builtin_amdgcn_global_load_lds(
        (const __attribute__((address_space(1))) void*)(src2 + off + l * 16),
        (__attribute__((address_space(3))) void*)(dst2 + off), 16, 0, 0);
    }
  };

  // ---- prologue: stage chunk 0; b1 slice -> LDS; X fragments -> VGPR ----
  stage(hbase, 0);
  for (int i = tid; i < HSLICE; i += 256) b1s[i] = b1g[e * HID + hbase + i];

  s16x8 xa[8];
  {
    int row = wm * 16 + lr;
    int grow = t * MTILE + row;
    int entry = (grow < cnt) ? mylist[row] : mylist[0];
    const unsigned short* xsrc = xbf + (size_t)(entry >> 1) * DIM;
    #pragma unroll
    for (int kb = 0; kb < 8; ++kb)
      xa[kb] = *(const s16x8*)(xsrc + kb * 32 + kg);
  }

  f32x4 acc[8] = {};
  #pragma unroll
  for (int n = 0; n < 8; ++n) initfence(acc[n]);

  __syncthreads();   // prologue drain (once): stage(0), b1s, xa all complete

  int swz = (lr & 7) << 3;
  int brow = (wn * 16 + lr) << 8;   // W1b row base (256 elems/row)

  #pragma unroll 2
  for (int c = 0; c < NCHUNK; ++c) {
    int buf = c & 1;

    // top: wait for stage(c) (issued one full chunk body ago), all-wave barrier.
    asm volatile("s_waitcnt vmcnt(0)" ::: "memory");
    __builtin_amdgcn_s_barrier();
    __builtin_amdgcn_sched_barrier(0);

    if (c + 1 < NCHUNK) stage(hbase + (c + 1) * HC, buf ^ 1);

    // GEMM1: h(32 x 32) = X @ W1chunk^T ; A in regs, B in LDS (swizzled)
    f32x4 h0 = {}, h1 = {};
    initfence(h0); initfence(h1);
    const short* w1p = &W1b[buf][0];
    #pragma unroll
    for (int kb = 0; kb < 8; ++kb) {
      s16x8 bv = *(const s16x8*)&w1p[brow + ((kb * 32 + kg) ^ swz)];
      if (kb & 1) mfma16(h1, xa[kb], bv); else mfma16(h0, xa[kb], bv);
    }
    accfence(h0); accfence(h1);
    h0 += h1;
    float bb = b1s[c * HC + wn * 16 + lr];
    #pragma unroll
    for (int q = 0; q < 4; ++q)
      hs[buf][wm * 16 + lg * 4 + q][wn * 16 + lr] = (short)f2bf(fmaxf(h0[q] + bb, 0.f));

    asm volatile("s_waitcnt lgkmcnt(0)" ::: "memory");
    __builtin_amdgcn_s_barrier();
    __builtin_amdgcn_sched_barrier(0);

    // GEMM2: y(32 x 256) += h @ W2chunk^T (k = 32, slot-swizzled B reads)
    {
      s16x8 a0 = *(const s16x8*)&hs[buf][wm * 16 + lr][kg];
      const short* w2p = &W2b[buf][0];
      #pragma unroll
      for (int n = 0; n < 8; ++n) {
        int d = wn * 128 + n * 16 + lr;
        s16x8 bv = *(const s16x8*)&w2p[(d << 5) + ((lg ^ ((d >> 1) & 3)) << 3)];
        mfma16(acc[n], a0, bv);
      }
    }
    // no end barrier: next top barrier orders GEMM2 reads vs stage(c+2) writes;
    // hs double-buffered for the GEMM1(c+1) overlap.
  }

  // ---- epilogue: bf16 partial store to slot buffer (+b2 on slice 0) ----
  #pragma unroll
  for (int n = 0; n < 8; ++n) accfence(acc[n]);
  float b2v[8];
  #pragma unroll
  for (int n = 0; n < 8; ++n) b2v[n] = (s == 0) ? b2g[e * DIM + wn * 128 + n * 16 + lr] : 0.f;
  #pragma unroll
  for (int q = 0; q < 4; ++q) {
    int lrow = wm * 16 + lg * 4 + q;
    int grow = t * MTILE + lrow;
    if (grow < cnt) {
      int entry = mylist[lrow];
      unsigned short* yrow = ybuf + ((size_t)entry * NSLICE + s) * DIM + wn * 128 + lr;
      #pragma unroll
      for (int n = 0; n < 8; ++n)
        yrow[n * 16] = f2bf(acc[n][q] + b2v[n]);
    }
  }
}

// ---- out[n][d] = sum of 4 slot-rows of bf16 ybuf ----
__global__ __launch_bounds__(256) void reduce4(const unsigned short* __restrict__ yb,
                                               float* __restrict__ out) {
  int i = (blockIdx.x * 256 + threadIdx.x) * 8;
  int n = i >> 8, d = i & 255;
  const unsigned short* base = yb + ((size_t)n * 4) * DIM + d;
  float sum[8] = {0,0,0,0,0,0,0,0};
  #pragma unroll
  for (int r = 0; r < 4; ++r) {
    s16x8 v = *(const s16x8*)(base + r * DIM);
    #pragma unroll
    for (int j = 0; j < 8; ++j) sum[j] += bf2f((unsigned short)v[j]);
  }
  float4 o0 = {sum[0], sum[1], sum[2], sum[3]};
  float4 o1 = {sum[4], sum[5], sum[6], sum[7]};
  *(float4*)(out + i) = o0;
  *(float4*)(out + i + 4) = o1;
}

extern "C" void kernel_launch(void* const* d_in, const int* in_sizes, int n_in,
                              void* d_out, int out_size, void* d_ws, size_t ws_size,
                              hipStream_t stream) {
  const float* x    = (const float*)d_in[0];
  const float* gW   = (const float*)d_in[1];
  const float* gb   = (const float*)d_in[2];
  const float* W1   = (const float*)d_in[3];
  const float* b1   = (const float*)d_in[4];
  const float* W2   = (const float*)d_in[5];
  const float* b2   = (const float*)d_in[6];
  const float* temp = (const float*)d_in[7];
  float* out = (float*)d_out;

  char* ws = (char*)d_ws;
  int*            counts = (int*)(ws + 0);                      // 256 B
  int*            list   = (int*)(ws + 256);                    // 128 KB
  unsigned short* xbf    = (unsigned short*)(ws + 131584);      // 2 MB
  unsigned short* W1T    = (unsigned short*)(ws + 2228736);     // 4 MB
  unsigned short* W2T    = (unsigned short*)(ws + 6423040);     // 4 MB
  unsigned short* ybuf   = (unsigned short*)(ws + 10617344);    // 8 MB bf16

  prep<<<4096, dim3(32, 8, 1), 0, stream>>>(W1, W2, W1T, W2T, counts);
  gate_route<<<NTOK/16, 256, 0, stream>>>(x, gW, gb, temp, counts, list, xbf);
  moe_ffn<<<NEXP * (NTOK/MTILE) * NSLICE, 256, 0, stream>>>(xbf, W1T, W2T, b1, b2, counts, list, ybuf);
  reduce4<<<NTOK*DIM/2048, 256, 0, stream>>>(ybuf, out);
}

// Round 11
// 56.233 us; speedup vs baseline: 1.0874x; 1.0874x over previous
//
#include <hip/hip_runtime.h>
#include <hip/hip_bf16.h>
#include <stdint.h>

#define NTOK 4096
#define DIM  256
#define HID  1024
#define NEXP 8
#define MTILE 32
#define HC 32
#define HSLICE 512
#define NSLICE 2
#define NCHUNK (HSLICE / HC)   // 16

typedef float f32x4 __attribute__((ext_vector_type(4)));
typedef short s16x8 __attribute__((ext_vector_type(8)));

__device__ __forceinline__ unsigned short f2bf(float f) {
  union { float f; unsigned u; } v; v.f = f;
  unsigned r = v.u + 0x7FFFu + ((v.u >> 16) & 1u);
  return (unsigned short)(r >> 16);
}
__device__ __forceinline__ float bf2f(unsigned short s) {
  union { float f; unsigned u; } v; v.u = ((unsigned)s) << 16;
  return v.f;
}
__device__ __forceinline__ void mfma16(f32x4& acc, s16x8 a, s16x8 b) {
  asm("v_mfma_f32_16x16x32_bf16 %0, %1, %2, %0" : "+v"(acc) : "v"(a), "v"(b));
}
__device__ __forceinline__ void accfence(f32x4& a) {   // MFMA->VALU read hazard
  asm volatile("s_nop 7" : "+v"(a));
}
__device__ __forceinline__ void initfence(f32x4& a) {  // VALU init -> MFMA srcC hazard
  asm volatile("s_nop 1" : "+v"(a));
}

// ---- merged prep: transpose + bf16 + swizzle; zero counts ----
// W1 [E][256][1024] f32 -> W1T [E][1024][256] bf16, col' = col ^ ((row&7)<<3)
// W2 [E][1024][256] f32 -> W2T chunk-tiled [E][H/32][D][32] bf16, CONTIGUOUS 16 KB
//   per (e,chunk); within a d-row the 8-elem slot is XORed: slot' = slot ^ ((d>>1)&3)
__global__ __launch_bounds__(256) void prep(const float* __restrict__ W1,
                                            const float* __restrict__ W2,
                                            unsigned short* __restrict__ W1T,
                                            unsigned short* __restrict__ W2T,
                                            int* __restrict__ counts) {
  __shared__ float tile[32][33];
  int id = blockIdx.x;
  int tx = threadIdx.x, ty = threadIdx.y;
  if (id == 0 && ty == 0 && tx < NEXP) counts[tx] = 0;

  const float* in; unsigned short* out; int R, C, bx, by, e, sw;
  if (id < 2048) {            // W1 job: in R=256 x C=1024
    e = id >> 8; int rem = id & 255; by = rem >> 5; bx = rem & 31;
    in = W1; out = W1T; R = 256; C = 1024; sw = 1;
  } else {                    // W2 job: in R=1024 x C=256
    int id2 = id - 2048;
    e = id2 >> 8; int rem = id2 & 255; by = (rem >> 3) & 31; bx = rem & 7;
    in = W2; out = W2T; R = 1024; C = 256; sw = 0;
  }
  int r0 = by * 32, c0 = bx * 32;
  const float* ip = in + (size_t)e * R * C;
  unsigned short* op = out + (size_t)e * R * C;
  #pragma unroll
  for (int k = 0; k < 4; ++k)
    tile[ty + 8*k][tx] = ip[(size_t)(r0 + ty + 8*k) * C + c0 + tx];
  __syncthreads();
  #pragma unroll
  for (int k = 0; k < 4; ++k) {
    float v = tile[tx][ty + 8*k];
    if (sw) {
      int row = c0 + ty + 8*k;   // h
      int col = r0 + tx;         // d
      op[(size_t)row * R + (col ^ ((row & 7) << 3))] = f2bf(v);
    } else {
      int d = c0 + ty + 8*k;     // output d (input col)
      int h = r0 + tx;           // input row
      int ch = h >> 5, kk = h & 31;
      int slot = (kk >> 3) ^ ((d >> 1) & 3);
      op[(size_t)ch * (DIM * 32) + d * 32 + slot * 8 + (kk & 7)] = f2bf(v);
    }
  }
}

// ---- gate + top-2 + block-aggregated routing (16 tokens/block, 16 lanes/token) ----
// list entries encode token*2 + slot
__global__ __launch_bounds__(256) void gate_route(const float* __restrict__ x,
    const float* __restrict__ gW, const float* __restrict__ gb,
    const float* __restrict__ temp,
    int* __restrict__ counts, int* __restrict__ list,
    unsigned short* __restrict__ xbf) {
  __shared__ int pairs[16][2];
  __shared__ int lcnt[NEXP], lbase[NEXP], lrank[NEXP];
  int tid = threadIdx.x;
  int w = tid >> 6, lane = tid & 63;
  int sl = lane & 15, g = lane >> 4;
  if (tid < NEXP) { lcnt[tid] = 0; lrank[tid] = 0; }
  __syncthreads();
  int t0 = blockIdx.x * 16;
  int tok = w * 4 + g;
  int n = t0 + tok;

  float4 xv[4];
  #pragma unroll
  for (int p = 0; p < 4; ++p)
    xv[p] = *reinterpret_cast<const float4*>(x + (size_t)n * DIM + sl * 16 + p * 4);
  {
    s16x8 xb0, xb1;
    xb0[0]=(short)f2bf(xv[0].x); xb0[1]=(short)f2bf(xv[0].y); xb0[2]=(short)f2bf(xv[0].z); xb0[3]=(short)f2bf(xv[0].w);
    xb0[4]=(short)f2bf(xv[1].x); xb0[5]=(short)f2bf(xv[1].y); xb0[6]=(short)f2bf(xv[1].z); xb0[7]=(short)f2bf(xv[1].w);
    xb1[0]=(short)f2bf(xv[2].x); xb1[1]=(short)f2bf(xv[2].y); xb1[2]=(short)f2bf(xv[2].z); xb1[3]=(short)f2bf(xv[2].w);
    xb1[4]=(short)f2bf(xv[3].x); xb1[5]=(short)f2bf(xv[3].y); xb1[6]=(short)f2bf(xv[3].z); xb1[7]=(short)f2bf(xv[3].w);
    *reinterpret_cast<s16x8*>(xbf + (size_t)n * DIM + sl * 16)     = xb0;
    *reinterpret_cast<s16x8*>(xbf + (size_t)n * DIM + sl * 16 + 8) = xb1;
  }
  float acc[NEXP];
  #pragma unroll
  for (int e = 0; e < NEXP; ++e) {
    const float* we = gW + (size_t)e * DIM + sl * 16;
    float a = 0.f;
    #pragma unroll
    for (int p = 0; p < 4; ++p) {
      float4 wv = *reinterpret_cast<const float4*>(we + p * 4);
      a += xv[p].x*wv.x + xv[p].y*wv.y + xv[p].z*wv.z + xv[p].w*wv.w;
    }
    acc[e] = a;
  }
  #pragma unroll
  for (int off = 1; off < 16; off <<= 1) {
    #pragma unroll
    for (int e = 0; e < NEXP; ++e) acc[e] += __shfl_xor(acc[e], off);
  }
  if (sl == 0) {
    float t = temp[0];
    float s[NEXP];
    #pragma unroll
    for (int e = 0; e < NEXP; ++e) s[e] = (acc[e] + gb[e]) / t;
    int b0 = 0; float v0 = s[0];
    #pragma unroll
    for (int e = 1; e < NEXP; ++e) if (s[e] > v0) { v0 = s[e]; b0 = e; }
    int b1i = 0; float v1 = -3.4e38f;
    #pragma unroll
    for (int e = 0; e < NEXP; ++e) if (e != b0 && s[e] > v1) { v1 = s[e]; b1i = e; }
    pairs[tok][0] = b0;
    pairs[tok][1] = b1i;
    atomicAdd(&lcnt[b0], 1);
    atomicAdd(&lcnt[b1i], 1);
  }
  __syncthreads();
  if (tid < NEXP) lbase[tid] = atomicAdd(&counts[tid], lcnt[tid]);
  __syncthreads();
  if (tid < 32) {
    int tk = tid >> 1;
    int e = pairs[tk][tid & 1];
    int r = atomicAdd(&lrank[e], 1);
    list[e * NTOK + lbase[e] + r] = (t0 + tk) * 2 + (tid & 1);
  }
}

// ---- fused FFN: single-barrier chunks, counted vmcnt(8), GEMM2 pipelined 1 behind ----
// iter c: [lgkm;bar] stage{W1(c+1),W2(c)} vmcnt(8) GEMM1(c)||GEMM2(c-1) h->hs[c&1]
__global__ __launch_bounds__(256, 2) void moe_ffn(
    const unsigned short* __restrict__ xbf,
    const unsigned short* __restrict__ W1T,  // [E][H][D] bf16, swizzled
    const unsigned short* __restrict__ W2T,  // [E][H/32][D][32] bf16, chunk-tiled
    const float* __restrict__ b1g, const float* __restrict__ b2g,
    const int* __restrict__ counts, const int* __restrict__ list,
    unsigned short* __restrict__ ybuf) {
  int b = blockIdx.x;
  int e = b & 7;
  int r = b >> 3;
  int s = r & (NSLICE - 1);
  int t = r >> 1;
  int cnt = counts[e];
  if (t * MTILE >= cnt) return;

  __shared__ __align__(16) short W1b[2][HC * 256];   // 32 KB
  __shared__ __align__(16) short W2b[2][256 * HC];   // 32 KB
  __shared__ __align__(16) short hs[2][32][40];      // 5 KB

  int tid = threadIdx.x;
  int l = tid & 63, w = tid >> 6;
  int lr = l & 15, lg = l >> 4, kg = lg * 8;
  int wm = w & 1, wn = w >> 1;   // GEMM1: tok-half16 x hcol-group16; GEMM2: tok-half16 x d-half128
  int hbase = s * HSLICE;
  const int* mylist = list + e * NTOK + t * MTILE;
  const unsigned short* W1e = W1T + (size_t)e * HID * DIM;
  const unsigned short* W2e = W2T + (size_t)e * HID * DIM;

  auto stage1 = [&](int hc, int buf) {   // W1 chunk: 16 KB linear
    const char* src = (const char*)(W1e + (size_t)hc * DIM);
    char* dst = (char*)&W1b[buf][0];
    #pragma unroll
    for (int i = 0; i < 4; ++i) {
      int off = w * 4096 + i * 1024;
      __builtin_amdgcn_global_load_lds(
        (const __attribute__((address_space(1))) void*)(src + off + l * 16),
        (__attribute__((address_space(3))) void*)(dst + off), 16, 0, 0);
    }
  };
  auto stage2 = [&](int hc, int buf) {   // W2 chunk: 16 KB linear (chunk-tiled image)
    const char* src = (const char*)(W2e + (size_t)(hc >> 5) * (DIM * 32));
    char* dst = (char*)&W2b[buf][0];
    #pragma unroll
    for (int i = 0; i < 4; ++i) {
      int off = w * 4096 + i * 1024;
      __builtin_amdgcn_global_load_lds(
        (const __attribute__((address_space(1))) void*)(src + off + l * 16),
        (__attribute__((address_space(3))) void*)(dst + off), 16, 0, 0);
    }
  };

  // ---- prologue: stage W1(0); b1 -> 16 VGPRs (static idx); X frags -> VGPR ----
  stage1(hbase, 0);

  float bbreg[NCHUNK];
  #pragma unroll
  for (int c = 0; c < NCHUNK; ++c)
    bbreg[c] = b1g[e * HID + hbase + c * HC + wn * 16 + lr];

  s16x8 xa[8];
  {
    int row = wm * 16 + lr;
    int grow = t * MTILE + row;
    int entry = (grow < cnt) ? mylist[row] : mylist[0];
    const unsigned short* xsrc = xbf + (size_t)(entry >> 1) * DIM;
    #pragma unroll
    for (int kb = 0; kb < 8; ++kb)
      xa[kb] = *(const s16x8*)(xsrc + kb * 32 + kg);
  }

  f32x4 acc[8] = {};
  #pragma unroll
  for (int n = 0; n < 8; ++n) initfence(acc[n]);

  __syncthreads();   // prologue drain once (stage1(0), bbreg, xa complete)

  int swz = (lr & 7) << 3;
  int brow = (wn * 16 + lr) << 8;   // W1b row base (256 elems/row)

  #pragma unroll
  for (int c = 0; c < NCHUNK; ++c) {
    int P = c & 1, Q = P ^ 1;

    // ---- single all-wave sync per chunk; LDS settled, loads stay in flight ----
    asm volatile("s_waitcnt lgkmcnt(0)" ::: "memory");
    __builtin_amdgcn_s_barrier();
    __builtin_amdgcn_sched_barrier(0);

    // stage next: W1(c+1) -> W1b[Q], W2(c) -> W2b[P]  (8 loads, NOT waited this iter)
    stage1(hbase + (((c + 1) & (NCHUNK - 1)) * HC), Q);
    stage2(hbase + c * HC, P);

    // counted wait: only last iter's 8 loads (W1(c), W2(c-1)) must be complete
    asm volatile("s_waitcnt vmcnt(8)" ::: "memory");
    __builtin_amdgcn_sched_barrier(0);

    // GEMM1(c): h(32x32) = X @ W1chunk^T  (A regs, B LDS swizzled)
    f32x4 h0 = {}, h1 = {};
    initfence(h0); initfence(h1);
    const short* w1p = &W1b[P][0];
    #pragma unroll
    for (int kb = 0; kb < 8; ++kb) {
      s16x8 bv = *(const s16x8*)&w1p[brow + ((kb * 32 + kg) ^ swz)];
      if (kb & 1) mfma16(h1, xa[kb], bv); else mfma16(h0, xa[kb], bv);
    }

    // GEMM2(c-1): y += h(c-1) @ W2(c-1)^T — independent of GEMM1, interleaves
    if (c > 0) {
      s16x8 a0 = *(const s16x8*)&hs[Q][wm * 16 + lr][kg];
      const short* w2p = &W2b[Q][0];
      #pragma unroll
      for (int n = 0; n < 8; ++n) {
        int d = wn * 128 + n * 16 + lr;
        s16x8 bv = *(const s16x8*)&w2p[(d << 5) + ((lg ^ ((d >> 1) & 3)) << 3)];
        mfma16(acc[n], a0, bv);
      }
    }

    // finish h(c): +b1, relu, write hs[P] for next iter
    accfence(h0); accfence(h1);
    h0 += h1;
    float bb = bbreg[c];
    #pragma unroll
    for (int q = 0; q < 4; ++q)
      hs[P][wm * 16 + lg * 4 + q][wn * 16 + lr] = (short)f2bf(fmaxf(h0[q] + bb, 0.f));
  }

  // ---- epilogue: GEMM2 for last chunk (15) ----
  asm volatile("s_waitcnt vmcnt(0) lgkmcnt(0)" ::: "memory");
  __builtin_amdgcn_s_barrier();
  __builtin_amdgcn_sched_barrier(0);
  {
    const int Q = (NCHUNK - 1) & 1;   // = 1
    s16x8 a0 = *(const s16x8*)&hs[Q][wm * 16 + lr][kg];
    const short* w2p = &W2b[Q][0];
    #pragma unroll
    for (int n = 0; n < 8; ++n) {
      int d = wn * 128 + n * 16 + lr;
      s16x8 bv = *(const s16x8*)&w2p[(d << 5) + ((lg ^ ((d >> 1) & 3)) << 3)];
      mfma16(acc[n], a0, bv);
    }
  }

  // ---- epilogue: bf16 partial store to slot buffer (+b2 on slice 0) ----
  #pragma unroll
  for (int n = 0; n < 8; ++n) accfence(acc[n]);
  float b2v[8];
  #pragma unroll
  for (int n = 0; n < 8; ++n) b2v[n] = (s == 0) ? b2g[e * DIM + wn * 128 + n * 16 + lr] : 0.f;
  #pragma unroll
  for (int q = 0; q < 4; ++q) {
    int lrow = wm * 16 + lg * 4 + q;
    int grow = t * MTILE + lrow;
    if (grow < cnt) {
      int entry = mylist[lrow];
      unsigned short* yrow = ybuf + ((size_t)entry * NSLICE + s) * DIM + wn * 128 + lr;
      #pragma unroll
      for (int n = 0; n < 8; ++n)
        yrow[n * 16] = f2bf(acc[n][q] + b2v[n]);
    }
  }
}

// ---- out[n][d] = sum of 4 slot-rows of bf16 ybuf ----
__global__ __launch_bounds__(256) void reduce4(const unsigned short* __restrict__ yb,
                                               float* __restrict__ out) {
  int i = (blockIdx.x * 256 + threadIdx.x) * 8;
  int n = i >> 8, d = i & 255;
  const unsigned short* base = yb + ((size_t)n * 4) * DIM + d;
  float sum[8] = {0,0,0,0,0,0,0,0};
  #pragma unroll
  for (int r = 0; r < 4; ++r) {
    s16x8 v = *(const s16x8*)(base + r * DIM);
    #pragma unroll
    for (int j = 0; j < 8; ++j) sum[j] += bf2f((unsigned short)v[j]);
  }
  float4 o0 = {sum[0], sum[1], sum[2], sum[3]};
  float4 o1 = {sum[4], sum[5], sum[6], sum[7]};
  *(float4*)(out + i) = o0;
  *(float4*)(out + i + 4) = o1;
}

extern "C" void kernel_launch(void* const* d_in, const int* in_sizes, int n_in,
                              void* d_out, int out_size, void* d_ws, size_t ws_size,
                              hipStream_t stream) {
  const float* x    = (const float*)d_in[0];
  const float* gW   = (const float*)d_in[1];
  const float* gb   = (const float*)d_in[2];
  const float* W1   = (const float*)d_in[3];
  const float* b1   = (const float*)d_in[4];
  const float* W2   = (const float*)d_in[5];
  const float* b2   = (const float*)d_in[6];
  const float* temp = (const float*)d_in[7];
  float* out = (float*)d_out;

  char* ws = (char*)d_ws;
  int*            counts = (int*)(ws + 0);                      // 256 B
  int*            list   = (int*)(ws + 256);                    // 128 KB
  unsigned short* xbf    = (unsigned short*)(ws + 131584);      // 2 MB
  unsigned short* W1T    = (unsigned short*)(ws + 2228736);     // 4 MB
  unsigned short* W2T    = (unsigned short*)(ws + 6423040);     // 4 MB
  unsigned short* ybuf   = (unsigned short*)(ws + 10617344);    // 8 MB bf16

  prep<<<4096, dim3(32, 8, 1), 0, stream>>>(W1, W2, W1T, W2T, counts);
  gate_route<<<NTOK/16, 256, 0, stream>>>(x, gW, gb, temp, counts, list, xbf);
  moe_ffn<<<NEXP * (NTOK/MTILE) * NSLICE, 256, 0, stream>>>(xbf, W1T, W2T, b1, b2, counts, list, ybuf);
  reduce4<<<NTOK*DIM/2048, 256, 0, stream>>>(ybuf, out);
}

// Round 12
// 52.640 us; speedup vs baseline: 1.1616x; 1.0683x over previous
//
#include <hip/hip_runtime.h>
#include <hip/hip_bf16.h>
#include <stdint.h>

#define NTOK 4096
#define DIM  256
#define HID  1024
#define NEXP 8
#define MTILE 64
#define HC 32
#define HSLICE 256
#define NSLICE 4
#define NCHUNK (HSLICE / HC)   // 8

typedef float f32x4 __attribute__((ext_vector_type(4)));
typedef short s16x8 __attribute__((ext_vector_type(8)));

__device__ __forceinline__ unsigned short f2bf(float f) {
  union { float f; unsigned u; } v; v.f = f;
  unsigned r = v.u + 0x7FFFu + ((v.u >> 16) & 1u);
  return (unsigned short)(r >> 16);
}
__device__ __forceinline__ float bf2f(unsigned short s) {
  union { float f; unsigned u; } v; v.u = ((unsigned)s) << 16;
  return v.f;
}
__device__ __forceinline__ void mfma16(f32x4& acc, s16x8 a, s16x8 b) {
  asm("v_mfma_f32_16x16x32_bf16 %0, %1, %2, %0" : "+v"(acc) : "v"(a), "v"(b));
}
__device__ __forceinline__ void accfence(f32x4& a) {   // MFMA->VALU read hazard
  asm volatile("s_nop 7" : "+v"(a));
}
__device__ __forceinline__ void initfence(f32x4& a) {  // VALU init -> MFMA srcC hazard
  asm volatile("s_nop 1" : "+v"(a));
}

// ---- merged prep: transpose + bf16 + swizzle; zero counts ----
// W1 [E][256][1024] f32 -> W1T [E][1024][256] bf16, col' = col ^ ((row&7)<<3)
// W2 [E][1024][256] f32 -> W2T chunk-tiled [E][H/32][D][32] bf16, CONTIGUOUS 16 KB
//   per (e,chunk); within a d-row the 8-elem slot is XORed: slot' = slot ^ ((d>>1)&3)
__global__ __launch_bounds__(256) void prep(const float* __restrict__ W1,
                                            const float* __restrict__ W2,
                                            unsigned short* __restrict__ W1T,
                                            unsigned short* __restrict__ W2T,
                                            int* __restrict__ counts) {
  __shared__ float tile[32][33];
  int id = blockIdx.x;
  int tx = threadIdx.x, ty = threadIdx.y;
  if (id == 0 && ty == 0 && tx < NEXP) counts[tx] = 0;

  const float* in; unsigned short* out; int R, C, bx, by, e, sw;
  if (id < 2048) {            // W1 job: in R=256 x C=1024
    e = id >> 8; int rem = id & 255; by = rem >> 5; bx = rem & 31;
    in = W1; out = W1T; R = 256; C = 1024; sw = 1;
  } else {                    // W2 job: in R=1024 x C=256
    int id2 = id - 2048;
    e = id2 >> 8; int rem = id2 & 255; by = (rem >> 3) & 31; bx = rem & 7;
    in = W2; out = W2T; R = 1024; C = 256; sw = 0;
  }
  int r0 = by * 32, c0 = bx * 32;
  const float* ip = in + (size_t)e * R * C;
  unsigned short* op = out + (size_t)e * R * C;
  #pragma unroll
  for (int k = 0; k < 4; ++k)
    tile[ty + 8*k][tx] = ip[(size_t)(r0 + ty + 8*k) * C + c0 + tx];
  __syncthreads();
  #pragma unroll
  for (int k = 0; k < 4; ++k) {
    float v = tile[tx][ty + 8*k];
    if (sw) {
      int row = c0 + ty + 8*k;   // h
      int col = r0 + tx;         // d
      op[(size_t)row * R + (col ^ ((row & 7) << 3))] = f2bf(v);
    } else {
      int d = c0 + ty + 8*k;     // output d (input col)
      int h = r0 + tx;           // input row
      int ch = h >> 5, kk = h & 31;
      int slot = (kk >> 3) ^ ((d >> 1) & 3);
      op[(size_t)ch * (DIM * 32) + d * 32 + slot * 8 + (kk & 7)] = f2bf(v);
    }
  }
}

// ---- gate + top-2 + block-aggregated routing (16 tokens/block, 16 lanes/token) ----
// list entries encode token*2 + slot
__global__ __launch_bounds__(256) void gate_route(const float* __restrict__ x,
    const float* __restrict__ gW, const float* __restrict__ gb,
    const float* __restrict__ temp,
    int* __restrict__ counts, int* __restrict__ list,
    unsigned short* __restrict__ xbf) {
  __shared__ int pairs[16][2];
  __shared__ int lcnt[NEXP], lbase[NEXP], lrank[NEXP];
  int tid = threadIdx.x;
  int w = tid >> 6, lane = tid & 63;
  int sl = lane & 15, g = lane >> 4;
  if (tid < NEXP) { lcnt[tid] = 0; lrank[tid] = 0; }
  __syncthreads();
  int t0 = blockIdx.x * 16;
  int tok = w * 4 + g;
  int n = t0 + tok;

  float4 xv[4];
  #pragma unroll
  for (int p = 0; p < 4; ++p)
    xv[p] = *reinterpret_cast<const float4*>(x + (size_t)n * DIM + sl * 16 + p * 4);
  {
    s16x8 xb0, xb1;
    xb0[0]=(short)f2bf(xv[0].x); xb0[1]=(short)f2bf(xv[0].y); xb0[2]=(short)f2bf(xv[0].z); xb0[3]=(short)f2bf(xv[0].w);
    xb0[4]=(short)f2bf(xv[1].x); xb0[5]=(short)f2bf(xv[1].y); xb0[6]=(short)f2bf(xv[1].z); xb0[7]=(short)f2bf(xv[1].w);
    xb1[0]=(short)f2bf(xv[2].x); xb1[1]=(short)f2bf(xv[2].y); xb1[2]=(short)f2bf(xv[2].z); xb1[3]=(short)f2bf(xv[2].w);
    xb1[4]=(short)f2bf(xv[3].x); xb1[5]=(short)f2bf(xv[3].y); xb1[6]=(short)f2bf(xv[3].z); xb1[7]=(short)f2bf(xv[3].w);
    *reinterpret_cast<s16x8*>(xbf + (size_t)n * DIM + sl * 16)     = xb0;
    *reinterpret_cast<s16x8*>(xbf + (size_t)n * DIM + sl * 16 + 8) = xb1;
  }
  float acc[NEXP];
  #pragma unroll
  for (int e = 0; e < NEXP; ++e) {
    const float* we = gW + (size_t)e * DIM + sl * 16;
    float a = 0.f;
    #pragma unroll
    for (int p = 0; p < 4; ++p) {
      float4 wv = *reinterpret_cast<const float4*>(we + p * 4);
      a += xv[p].x*wv.x + xv[p].y*wv.y + xv[p].z*wv.z + xv[p].w*wv.w;
    }
    acc[e] = a;
  }
  #pragma unroll
  for (int off = 1; off < 16; off <<= 1) {
    #pragma unroll
    for (int e = 0; e < NEXP; ++e) acc[e] += __shfl_xor(acc[e], off);
  }
  if (sl == 0) {
    float t = temp[0];
    float s[NEXP];
    #pragma unroll
    for (int e = 0; e < NEXP; ++e) s[e] = (acc[e] + gb[e]) / t;
    int b0 = 0; float v0 = s[0];
    #pragma unroll
    for (int e = 1; e < NEXP; ++e) if (s[e] > v0) { v0 = s[e]; b0 = e; }
    int b1i = 0; float v1 = -3.4e38f;
    #pragma unroll
    for (int e = 0; e < NEXP; ++e) if (e != b0 && s[e] > v1) { v1 = s[e]; b1i = e; }
    pairs[tok][0] = b0;
    pairs[tok][1] = b1i;
    atomicAdd(&lcnt[b0], 1);
    atomicAdd(&lcnt[b1i], 1);
  }
  __syncthreads();
  if (tid < NEXP) lbase[tid] = atomicAdd(&counts[tid], lcnt[tid]);
  __syncthreads();
  if (tid < 32) {
    int tk = tid >> 1;
    int e = pairs[tk][tid & 1];
    int r = atomicAdd(&lrank[e], 1);
    list[e * NTOK + lbase[e] + r] = (t0 + tk) * 2 + (tid & 1);
  }
}

// ---- fused FFN: 64 tokens/block, 2 tok-groups/wave, single-barrier counted-vmcnt pipe ----
// iter c: [lgkm;bar] stage{W1(c+1),W2(c)} vmcnt(8) GEMM1(c)||GEMM2(c-1) h->hs[c&1]
__global__ __launch_bounds__(256, 2) void moe_ffn(
    const unsigned short* __restrict__ xbf,
    const unsigned short* __restrict__ W1T,  // [E][H][D] bf16, swizzled
    const unsigned short* __restrict__ W2T,  // [E][H/32][D][32] bf16, chunk-tiled
    const float* __restrict__ b1g, const float* __restrict__ b2g,
    const int* __restrict__ counts, const int* __restrict__ list,
    unsigned short* __restrict__ ybuf) {
  int b = blockIdx.x;
  int e = b & 7;
  int r = b >> 3;
  int s = r & (NSLICE - 1);
  int t = r >> 2;
  int cnt = counts[e];
  if (t * MTILE >= cnt) return;

  __shared__ __align__(16) short W1b[2][HC * 256];   // 32 KB
  __shared__ __align__(16) short W2b[2][256 * HC];   // 32 KB
  __shared__ __align__(16) short hs[2][64][40];      // 10 KB

  int tid = threadIdx.x;
  int l = tid & 63, w = tid >> 6;
  int lr = l & 15, lg = l >> 4, kg = lg * 8;
  int wm = w & 1, wn = w >> 1;   // wm: token-half (2 groups of 16); wn: hcol-16 / d-128
  int hbase = s * HSLICE;
  const int* mylist = list + e * NTOK + t * MTILE;
  const unsigned short* W1e = W1T + (size_t)e * HID * DIM;
  const unsigned short* W2e = W2T + (size_t)e * HID * DIM;

  auto stage1 = [&](int hc, int buf) {   // W1 chunk: 16 KB linear
    const char* src = (const char*)(W1e + (size_t)hc * DIM);
    char* dst = (char*)&W1b[buf][0];
    #pragma unroll
    for (int i = 0; i < 4; ++i) {
      int off = w * 4096 + i * 1024;
      __builtin_amdgcn_global_load_lds(
        (const __attribute__((address_space(1))) void*)(src + off + l * 16),
        (__attribute__((address_space(3))) void*)(dst + off), 16, 0, 0);
    }
  };
  auto stage2 = [&](int hc, int buf) {   // W2 chunk: 16 KB linear (chunk-tiled image)
    const char* src = (const char*)(W2e + (size_t)(hc >> 5) * (DIM * 32));
    char* dst = (char*)&W2b[buf][0];
    #pragma unroll
    for (int i = 0; i < 4; ++i) {
      int off = w * 4096 + i * 1024;
      __builtin_amdgcn_global_load_lds(
        (const __attribute__((address_space(1))) void*)(src + off + l * 16),
        (__attribute__((address_space(3))) void*)(dst + off), 16, 0, 0);
    }
  };

  // ---- prologue: stage W1(0); b1 -> VGPRs (static idx); X frags (2 groups) -> VGPR ----
  stage1(hbase, 0);

  float bbreg[NCHUNK];
  #pragma unroll
  for (int c = 0; c < NCHUNK; ++c)
    bbreg[c] = b1g[e * HID + hbase + c * HC + wn * 16 + lr];

  s16x8 xa[2][8];
  #pragma unroll
  for (int mf = 0; mf < 2; ++mf) {
    int row = (wm * 2 + mf) * 16 + lr;
    int grow = t * MTILE + row;
    int entry = (grow < cnt) ? mylist[row] : mylist[0];
    const unsigned short* xsrc = xbf + (size_t)(entry >> 1) * DIM;
    #pragma unroll
    for (int kb = 0; kb < 8; ++kb)
      xa[mf][kb] = *(const s16x8*)(xsrc + kb * 32 + kg);
  }

  f32x4 acc[2][8] = {};
  #pragma unroll
  for (int mf = 0; mf < 2; ++mf) {
    #pragma unroll
    for (int n = 0; n < 8; ++n) initfence(acc[mf][n]);
  }

  __syncthreads();   // prologue drain once (stage1(0), bbreg, xa complete)

  int swz = (lr & 7) << 3;
  int brow = (wn * 16 + lr) << 8;   // W1b row base (256 elems/row)

  #pragma unroll
  for (int c = 0; c < NCHUNK; ++c) {
    int P = c & 1, Q = P ^ 1;

    // ---- single all-wave sync per chunk; LDS settled, loads stay in flight ----
    asm volatile("s_waitcnt lgkmcnt(0)" ::: "memory");
    __builtin_amdgcn_s_barrier();
    __builtin_amdgcn_sched_barrier(0);

    // stage next: W1(c+1) -> W1b[Q], W2(c) -> W2b[P]  (8 loads, NOT waited this iter)
    stage1(hbase + (((c + 1) & (NCHUNK - 1)) * HC), Q);
    stage2(hbase + c * HC, P);

    // counted wait: only last iter's 8 loads (W1(c), W2(c-1)) must be complete
    asm volatile("s_waitcnt vmcnt(8)" ::: "memory");
    __builtin_amdgcn_sched_barrier(0);

    // GEMM1(c): h(64x32) = X @ W1chunk^T  (A regs x2 groups, B LDS swizzled, shared)
    f32x4 h0[2] = {}, h1[2] = {};
    initfence(h0[0]); initfence(h0[1]); initfence(h1[0]); initfence(h1[1]);
    const short* w1p = &W1b[P][0];
    #pragma unroll
    for (int kb = 0; kb < 8; ++kb) {
      s16x8 bv = *(const s16x8*)&w1p[brow + ((kb * 32 + kg) ^ swz)];
      if (kb & 1) { mfma16(h1[0], xa[0][kb], bv); mfma16(h1[1], xa[1][kb], bv); }
      else        { mfma16(h0[0], xa[0][kb], bv); mfma16(h0[1], xa[1][kb], bv); }
    }

    // GEMM2(c-1): y += h(c-1) @ W2(c-1)^T — independent of GEMM1, interleaves
    if (c > 0) {
      s16x8 a0 = *(const s16x8*)&hs[Q][(wm * 2 + 0) * 16 + lr][kg];
      s16x8 a1 = *(const s16x8*)&hs[Q][(wm * 2 + 1) * 16 + lr][kg];
      const short* w2p = &W2b[Q][0];
      #pragma unroll
      for (int n = 0; n < 8; ++n) {
        int d = wn * 128 + n * 16 + lr;
        s16x8 bv = *(const s16x8*)&w2p[(d << 5) + ((lg ^ ((d >> 1) & 3)) << 3)];
        mfma16(acc[0][n], a0, bv);
        mfma16(acc[1][n], a1, bv);
      }
    }

    // finish h(c): +b1, relu, write hs[P] for next iter
    accfence(h0[0]); accfence(h0[1]); accfence(h1[0]); accfence(h1[1]);
    float bb = bbreg[c];
    #pragma unroll
    for (int mf = 0; mf < 2; ++mf) {
      f32x4 h = h0[mf] + h1[mf];
      #pragma unroll
      for (int q = 0; q < 4; ++q)
        hs[P][(wm * 2 + mf) * 16 + lg * 4 + q][wn * 16 + lr] = (short)f2bf(fmaxf(h[q] + bb, 0.f));
    }
  }

  // ---- epilogue: GEMM2 for last chunk ----
  asm volatile("s_waitcnt vmcnt(0) lgkmcnt(0)" ::: "memory");
  __builtin_amdgcn_s_barrier();
  __builtin_amdgcn_sched_barrier(0);
  {
    const int Q = (NCHUNK - 1) & 1;   // = 1
    s16x8 a0 = *(const s16x8*)&hs[Q][(wm * 2 + 0) * 16 + lr][kg];
    s16x8 a1 = *(const s16x8*)&hs[Q][(wm * 2 + 1) * 16 + lr][kg];
    const short* w2p = &W2b[Q][0];
    #pragma unroll
    for (int n = 0; n < 8; ++n) {
      int d = wn * 128 + n * 16 + lr;
      s16x8 bv = *(const s16x8*)&w2p[(d << 5) + ((lg ^ ((d >> 1) & 3)) << 3)];
      mfma16(acc[0][n], a0, bv);
      mfma16(acc[1][n], a1, bv);
    }
  }

  // ---- epilogue: bf16 partial store to slot buffer (+b2 on slice 0) ----
  #pragma unroll
  for (int mf = 0; mf < 2; ++mf) {
    #pragma unroll
    for (int n = 0; n < 8; ++n) accfence(acc[mf][n]);
  }
  float b2v[8];
  #pragma unroll
  for (int n = 0; n < 8; ++n) b2v[n] = (s == 0) ? b2g[e * DIM + wn * 128 + n * 16 + lr] : 0.f;
  #pragma unroll
  for (int mf = 0; mf < 2; ++mf) {
    #pragma unroll
    for (int q = 0; q < 4; ++q) {
      int lrow = (wm * 2 + mf) * 16 + lg * 4 + q;
      int grow = t * MTILE + lrow;
      if (grow < cnt) {
        int entry = mylist[lrow];
        unsigned short* yrow = ybuf + ((size_t)entry * NSLICE + s) * DIM + wn * 128 + lr;
        #pragma unroll
        for (int n = 0; n < 8; ++n)
          yrow[n * 16] = f2bf(acc[mf][n][q] + b2v[n]);
      }
    }
  }
}

// ---- out[n][d] = sum of 8 slot-rows of bf16 ybuf ----
__global__ __launch_bounds__(256) void reduce8(const unsigned short* __restrict__ yb,
                                               float* __restrict__ out) {
  int i = (blockIdx.x * 256 + threadIdx.x) * 8;
  int n = i >> 8, d = i & 255;
  const unsigned short* base = yb + ((size_t)n * 8) * DIM + d;
  float sum[8] = {0,0,0,0,0,0,0,0};
  #pragma unroll
  for (int r = 0; r < 8; ++r) {
    s16x8 v = *(const s16x8*)(base + r * DIM);
    #pragma unroll
    for (int j = 0; j < 8; ++j) sum[j] += bf2f((unsigned short)v[j]);
  }
  float4 o0 = {sum[0], sum[1], sum[2], sum[3]};
  float4 o1 = {sum[4], sum[5], sum[6], sum[7]};
  *(float4*)(out + i) = o0;
  *(float4*)(out + i + 4) = o1;
}

extern "C" void kernel_launch(void* const* d_in, const int* in_sizes, int n_in,
                              void* d_out, int out_size, void* d_ws, size_t ws_size,
                              hipStream_t stream) {
  const float* x    = (const float*)d_in[0];
  const float* gW   = (const float*)d_in[1];
  const float* gb   = (const float*)d_in[2];
  const float* W1   = (const float*)d_in[3];
  const float* b1   = (const float*)d_in[4];
  const float* W2   = (const float*)d_in[5];
  const float* b2   = (const float*)d_in[6];
  const float* temp = (const float*)d_in[7];
  float* out = (float*)d_out;

  char* ws = (char*)d_ws;
  int*            counts = (int*)(ws + 0);                      // 256 B
  int*            list   = (int*)(ws + 256);                    // 128 KB
  unsigned short* xbf    = (unsigned short*)(ws + 131584);      // 2 MB
  unsigned short* W1T    = (unsigned short*)(ws + 2228736);     // 4 MB
  unsigned short* W2T    = (unsigned short*)(ws + 6423040);     // 4 MB
  unsigned short* ybuf   = (unsigned short*)(ws + 10617344);    // 16 MB bf16 (8 slots/token)

  prep<<<4096, dim3(32, 8, 1), 0, stream>>>(W1, W2, W1T, W2T, counts);
  gate_route<<<NTOK/16, 256, 0, stream>>>(x, gW, gb, temp, counts, list, xbf);
  moe_ffn<<<NEXP * (NTOK/MTILE) * NSLICE, 256, 0, stream>>>(xbf, W1T, W2T, b1, b2, counts, list, ybuf);
  reduce8<<<NTOK*DIM/2048, 256, 0, stream>>>(ybuf, out);
}